// Round 11
// baseline (226.558 us; speedup 1.0000x reference)
//
#include <hip/hip_runtime.h>
#include <hip/hip_bf16.h>
#include <math.h>

#define N_NODES 50000
#define N_EDGES 800000
#define ET_EDGES (N_EDGES + N_NODES)   // with self-loops
#define NEG_SLOPE 0.2f
#define NBUCK ((N_NODES + 255) / 256)  // 196 dst buckets (256 nodes each)
#define CHUNK 4096                      // edges per binning block
#define CAP   8192                      // scratch slots per bucket (>50 sigma)
#define BIN_GRID ((ET_EDGES + CHUNK - 1) / CHUNK)   // 208
#define GEMM_GRID ((N_NODES + 63) / 64)             // 782
#define GAT_GRID (N_NODES / 16)                     // 3125 exact

typedef __hip_bfloat16 bf16;
typedef float f32x2 __attribute__((ext_vector_type(2)));
typedef __attribute__((ext_vector_type(8))) short bf16x8v;  // MFMA A/B frag
typedef __attribute__((ext_vector_type(4))) float f32x4v;   // MFMA C/D frag

__device__ inline float bfbits(unsigned short u) {
    return __uint_as_float(((unsigned)u) << 16);
}
__device__ inline float bflo(unsigned u) { return __uint_as_float(u << 16); }
__device__ inline float bfhi(unsigned u) { return __uint_as_float(u & 0xffff0000u); }
__device__ inline f32x2 unpk(unsigned u) {
    f32x2 r; r.x = bflo(u); r.y = bfhi(u); return r;
}
__device__ inline f32x2 bcast2(float v) { f32x2 r; r.x = v; r.y = v; return r; }

// ---------------- prep: params + cursors + flag + MFMA-packed W1/W2/W3 ------
// y=0..11: convert 12 tensors; y=12: cursors+flag; y=13/14: W2/W3 -> B-frag
// split hi/lo (KS=2); y=15: W1 -> B-frag hi only (KS=4; used only when bf16
// input, where hi == exact raw W1).
// Pack layout (KS k-steps): idx = ((t*KS+s)*64 + ln)*8 + i
//   ->  B[k=32s+8*(ln>>4)+i][col=16t+(ln&15)]
struct PrepArgs {
    const void* src[12];
    float*      dst[12];
    int         n[12];
};

__global__ __launch_bounds__(256)
void prep(PrepArgs a, const unsigned short* __restrict__ w1raw,
          const void* __restrict__ w2raw, const void* __restrict__ w3raw,
          short* __restrict__ wb1, short* __restrict__ wb2,
          short* __restrict__ wb3,
          unsigned* __restrict__ flag, int* __restrict__ cur256)
{
    __shared__ unsigned sflag;
    const int tid = threadIdx.x;
    if (tid < 64) {
        float v0 = bfbits(w1raw[2 * tid]);
        float v1 = bfbits(w1raw[2 * tid + 1]);
        bool bad = !(fabsf(v0) <= 64.f && fabsf(v1) <= 64.f);  // NaN -> bad
        unsigned long long b = __ballot(bad);
        if (tid == 0) sflag = (b == 0ull) ? 1u : 0u;
    }
    __syncthreads();
    const bool isbf = (sflag != 0u);
    const int which = blockIdx.y;

    if (which == 12) {
        int i = blockIdx.x * 256 + tid;
        if (i < NBUCK) cur256[i] = i * CAP;
        if (blockIdx.x == 0 && tid == 0) *flag = isbf ? 1u : 0u;
        return;
    }
    if (which == 13 || which == 14) {
        const void* praw = (which == 13) ? w2raw : w3raw;
        short* dstp = (which == 13) ? wb2 : wb3;
        for (int idx = blockIdx.x * 256 + tid; idx < 4096; idx += 8 * 256) {
            const int i  = idx & 7;
            const int ln = (idx >> 3) & 63;
            const int ts = idx >> 9;            // 0..7 (t*2+s)
            const int t  = ts >> 1, s = ts & 1;
            const int k   = s * 32 + (ln >> 4) * 8 + i;
            const int col = t * 16 + (ln & 15);
            float wv = isbf ? bfbits(((const unsigned short*)praw)[k * 64 + col])
                            : ((const float*)praw)[k * 64 + col];
            bf16 hi = __float2bfloat16(wv);
            float lof = wv - __bfloat162float(hi);
            dstp[idx]        = (short)__bfloat16_as_ushort(hi);
            dstp[4096 + idx] = (short)__bfloat16_as_ushort(__float2bfloat16(lof));
        }
        return;
    }
    if (which == 15) {       // W1 pack, KS=4, hi only
        for (int idx = blockIdx.x * 256 + tid; idx < 16384; idx += 8 * 256) {
            const int i  = idx & 7;
            const int ln = (idx >> 3) & 63;
            const int ts = idx >> 9;            // 0..31 (t*4+s)
            const int t  = ts >> 2, s = ts & 3;
            const int k   = s * 32 + (ln >> 4) * 8 + i;   // k < 128
            const int col = t * 16 + (ln & 15);
            float wv = isbf ? bfbits(w1raw[k * 64 + col])
                            : ((const float*)w1raw)[k * 64 + col];
            wb1[idx] = (short)__bfloat16_as_ushort(__float2bfloat16(wv));
        }
        return;
    }
    const int n = a.n[which];
    const void* s = a.src[which];
    float* d = a.dst[which];
    for (int i = blockIdx.x * 256 + tid; i < n; i += 8 * 256)
        d[i] = isbf ? bfbits(((const unsigned short*)s)[i])
                    : ((const float*)s)[i];
}

// ---------------- binpass body (fused with gemm1) ---------------------------
__device__ void binpass_body(unsigned char* smem, int bid,
                             const int* __restrict__ ei,
                             int* __restrict__ cur256,
                             unsigned* __restrict__ scratch)
{
    int* hist   = (int*)smem;                  // 196
    int* lpre   = hist + NBUCK;                // 197
    int* lcur   = lpre + NBUCK + 1;            // 196
    int* gbase  = lcur + NBUCK;                // 196
    int* scan_a = gbase + NBUCK;               // 256
    unsigned* entry = (unsigned*)(scan_a + 256); // 4096

    const int tid = threadIdx.x;
    const int e0  = bid * CHUNK;
    const int n   = min(CHUNK, ET_EDGES - e0);

    if (tid < NBUCK) hist[tid] = 0;
    __syncthreads();

    for (int k = tid; k < n; k += 256) {
        int e = e0 + k;
        int d = (e < N_EDGES) ? ei[N_EDGES + e] : e - N_EDGES;
        atomicAdd(&hist[d >> 8], 1);
    }
    __syncthreads();

    int v = (tid < NBUCK) ? hist[tid] : 0;
    scan_a[tid] = v;
    __syncthreads();
    for (int off = 1; off < 256; off <<= 1) {
        int t = (tid >= off) ? scan_a[tid - off] : 0;
        __syncthreads();
        scan_a[tid] += t;
        __syncthreads();
    }
    if (tid < NBUCK) lpre[tid] = scan_a[tid] - v;
    if (tid == NBUCK - 1) lpre[NBUCK] = scan_a[tid];
    if (tid < NBUCK) {
        gbase[tid] = v ? atomicAdd(&cur256[tid], v) : 0;
        lcur[tid] = 0;
    }
    __syncthreads();

    for (int k = tid; k < n; k += 256) {
        int e = e0 + k;
        int s, d;
        if (e < N_EDGES) { s = ei[e]; d = ei[N_EDGES + e]; }
        else             { s = d = e - N_EDGES; }
        int b = d >> 8;
        int p = atomicAdd(&lcur[b], 1);
        entry[lpre[b] + p] = ((unsigned)s << 8) | (unsigned)(d & 255);
    }
    __syncthreads();

    for (int i = tid; i < n; i += 256) {
        int lo = 0, hi = NBUCK;
        while (hi - lo > 1) {
            int mid = (lo + hi) >> 1;
            if (lpre[mid] <= i) lo = mid; else hi = mid;
        }
        scratch[gbase[lo] + (i - lpre[lo])] = entry[i];
    }
}

// ---------------- fine_scatter (standalone, R5-proven) ----------------------
__global__ __launch_bounds__(256)
void fine_scatter(const int* __restrict__ cur256,
                  const unsigned* __restrict__ scratch,
                  int* __restrict__ csr_src,
                  int* __restrict__ rowptr)
{
    __shared__ int scnt[256];
    __shared__ int cnt[256];
    __shared__ int pre[256];
    const int tid = threadIdx.x;
    const int b   = blockIdx.x;
    const int nb  = b * 256;
    const int nn  = min(256, N_NODES - nb);

    int bv = (tid < NBUCK) ? (cur256[tid] - tid * CAP) : 0;
    scnt[tid] = bv;
    __syncthreads();
    for (int off = 1; off < 256; off <<= 1) {
        int u = (tid >= off) ? scnt[tid - off] : 0;
        __syncthreads();
        scnt[tid] += u;
        __syncthreads();
    }
    const int gb = scnt[b] - (cur256[b] - b * CAP);   // exclusive prefix at b
    const int n  = cur256[b] - b * CAP;               // realized count
    const long seg = (long)b * CAP;

    cnt[tid] = 0;
    __syncthreads();
    for (int i = tid; i < n; i += 256)
        atomicAdd(&cnt[scratch[seg + i] & 255u], 1);
    __syncthreads();

    int v = cnt[tid];
    pre[tid] = v;
    __syncthreads();
    for (int off = 1; off < 256; off <<= 1) {
        int t = (tid >= off) ? pre[tid - off] : 0;
        __syncthreads();
        pre[tid] += t;
        __syncthreads();
    }
    int excl = pre[tid] - v + gb;
    if (tid < nn) rowptr[nb + tid] = excl;
    if (b == NBUCK - 1 && tid == 0) rowptr[N_NODES] = ET_EDGES;
    cnt[tid] = excl;    // reuse as cursors
    __syncthreads();

    for (int i = tid; i < n; i += 256) {
        unsigned e = scratch[seg + i];
        int p = atomicAdd(&cnt[e & 255u], 1);
        csr_src[p] = (int)(e >> 8);
    }
}

// ---------------- GEMM1 body (VALU fallback, fp32 input path only) ----------
template<int CIN, int XMODE>
__device__ void gemm_body(unsigned char* smem, int bid,
                          const void* __restrict__ x,
                          const float* __restrict__ W,
                          const float* __restrict__ a_src,
                          const float* __restrict__ a_dst,
                          const unsigned* __restrict__ flag,
                          bf16* __restrict__ hb,
                          float* __restrict__ as_out,
                          float* __restrict__ ad_out)
{
    constexpr int CINP = CIN + 4;
    float* sW = (float*)smem;                 // CIN*64
    float* sx = sW + CIN * 64;                // 64*CINP
    const bool isbf = (XMODE == 2) || (XMODE == 1 && *flag != 0u);
    const int tid  = threadIdx.x;
    const int colg = tid & 15;
    const int rowg = tid >> 4;
    const int c0   = colg * 4;
    const int r0l  = rowg * 4;
    const int row0 = bid * 64;

    for (int i = tid * 4; i < CIN * 64; i += 1024)
        *(float4*)&sW[i] = *(const float4*)&W[i];

    const long xbase = (long)row0 * CIN;
    const int  tile  = 64 * CIN;
    const int  limit = (N_NODES - row0) * CIN;   // multiple of 4
    if (isbf) {
        const unsigned short* xb = (const unsigned short*)x + xbase;
        for (int i = tid * 4; i < tile; i += 1024) {
            float4 v = {0.f, 0.f, 0.f, 0.f};
            if (i < limit) {
                ushort4 u = *(const ushort4*)&xb[i];
                v.x = bfbits(u.x); v.y = bfbits(u.y);
                v.z = bfbits(u.z); v.w = bfbits(u.w);
            }
            const int r = i / CIN, k = i & (CIN - 1);
            *(float4*)&sx[r * CINP + k] = v;
        }
    } else {
        const float* xf = (const float*)x + xbase;
        for (int i = tid * 4; i < tile; i += 1024) {
            float4 v = {0.f, 0.f, 0.f, 0.f};
            if (i < limit) v = *(const float4*)&xf[i];
            const int r = i / CIN, k = i & (CIN - 1);
            *(float4*)&sx[r * CINP + k] = v;
        }
    }
    __syncthreads();

    f32x2 acc[4][2];
#pragma unroll
    for (int r = 0; r < 4; ++r) {
        acc[r][0] = (f32x2){0.f, 0.f};
        acc[r][1] = (f32x2){0.f, 0.f};
    }

#pragma unroll 2
    for (int kk = 0; kk < CIN; kk += 4) {
        const float4 w0 = *(const float4*)&sW[(kk + 0) * 64 + c0];
        const float4 w1 = *(const float4*)&sW[(kk + 1) * 64 + c0];
        const float4 w2 = *(const float4*)&sW[(kk + 2) * 64 + c0];
        const float4 w3 = *(const float4*)&sW[(kk + 3) * 64 + c0];
        f32x2 w0lo; w0lo.x = w0.x; w0lo.y = w0.y;
        f32x2 w0hi; w0hi.x = w0.z; w0hi.y = w0.w;
        f32x2 w1lo; w1lo.x = w1.x; w1lo.y = w1.y;
        f32x2 w1hi; w1hi.x = w1.z; w1hi.y = w1.w;
        f32x2 w2lo; w2lo.x = w2.x; w2lo.y = w2.y;
        f32x2 w2hi; w2hi.x = w2.z; w2hi.y = w2.w;
        f32x2 w3lo; w3lo.x = w3.x; w3lo.y = w3.y;
        f32x2 w3hi; w3hi.x = w3.z; w3hi.y = w3.w;
#pragma unroll
        for (int r = 0; r < 4; ++r) {
            const float4 xv = *(const float4*)&sx[(r0l + r) * CINP + kk];
            acc[r][0] = __builtin_elementwise_fma(bcast2(xv.x), w0lo, acc[r][0]);
            acc[r][1] = __builtin_elementwise_fma(bcast2(xv.x), w0hi, acc[r][1]);
            acc[r][0] = __builtin_elementwise_fma(bcast2(xv.y), w1lo, acc[r][0]);
            acc[r][1] = __builtin_elementwise_fma(bcast2(xv.y), w1hi, acc[r][1]);
            acc[r][0] = __builtin_elementwise_fma(bcast2(xv.z), w2lo, acc[r][0]);
            acc[r][1] = __builtin_elementwise_fma(bcast2(xv.z), w2hi, acc[r][1]);
            acc[r][0] = __builtin_elementwise_fma(bcast2(xv.w), w3lo, acc[r][0]);
            acc[r][1] = __builtin_elementwise_fma(bcast2(xv.w), w3hi, acc[r][1]);
        }
    }

    const float4 sa4 = *(const float4*)&a_src[c0];
    const float4 sd4 = *(const float4*)&a_dst[c0];
#pragma unroll
    for (int r = 0; r < 4; ++r) {
        const int row = row0 + r0l + r;
        const float h0 = acc[r][0].x, h1 = acc[r][0].y;
        const float h2 = acc[r][1].x, h3 = acc[r][1].y;
        float vs = fmaf(h0, sa4.x, fmaf(h1, sa4.y, fmaf(h2, sa4.z, h3 * sa4.w)));
        float vd = fmaf(h0, sd4.x, fmaf(h1, sd4.y, fmaf(h2, sd4.z, h3 * sd4.w)));
#pragma unroll
        for (int off = 1; off < 16; off <<= 1) {
            vs += __shfl_xor(vs, off, 64);
            vd += __shfl_xor(vd, off, 64);
        }
        if (row < N_NODES) {
            uint2 u;
            u.x = ((unsigned)__bfloat16_as_ushort(__float2bfloat16(h0))) |
                  (((unsigned)__bfloat16_as_ushort(__float2bfloat16(h1))) << 16);
            u.y = ((unsigned)__bfloat16_as_ushort(__float2bfloat16(h2))) |
                  (((unsigned)__bfloat16_as_ushort(__float2bfloat16(h3))) << 16);
            *(uint2*)&((unsigned short*)hb)[(long)row * 64 + c0] = u;
            if (colg == 0) { as_out[row] = vs; ad_out[row] = vd; }
        }
    }
}

// ---------------- bf16 MFMA gemm body (KS k-steps; R10-proven at KS=2) ------
// A (row-major bf16): lane holds A[row=lane&15][k=s*32+(lane>>4)*8+i].
// B: prep-packed, (t*KS+s)*512 + lane*8; lo block at +2048*KS.
// C/D: col=lane&15, row=(lane>>4)*4+reg (m89-verified).
template<int KS>
__device__ void mfma_gemm_body(int bid,
                               const unsigned short* __restrict__ xb,
                               const short* __restrict__ Wb,
                               const float* __restrict__ a_src,
                               const float* __restrict__ a_dst,
                               bf16* __restrict__ hb,
                               float* __restrict__ as_out,
                               float* __restrict__ ad_out,
                               bool haslo)
{
    constexpr int CIN = KS * 32;
    const int tid  = threadIdx.x;
    const int lane = tid & 63;
    const int wv_  = tid >> 6;
    const int g    = lane >> 4;
    const int l15  = lane & 15;
    const int row0 = bid * 64 + wv_ * 16;

    const int ar = row0 + l15;
    const long abase = (long)((ar < N_NODES) ? ar : 0) * CIN + g * 8;
    bf16x8v a[KS];
#pragma unroll
    for (int s = 0; s < KS; ++s)
        a[s] = *(const bf16x8v*)&xb[abase + s * 32];

    f32x4v acc[4];
    float vsr[4] = {0.f, 0.f, 0.f, 0.f};
    float vdr[4] = {0.f, 0.f, 0.f, 0.f};
#pragma unroll
    for (int t = 0; t < 4; ++t) {
        const short* bp = &Wb[(t * KS) * 512 + lane * 8];
        f32x4v c = {0.f, 0.f, 0.f, 0.f};
#pragma unroll
        for (int s = 0; s < KS; ++s)
            c = __builtin_amdgcn_mfma_f32_16x16x32_bf16(
                    a[s], *(const bf16x8v*)(bp + s * 512), c, 0, 0, 0);
        if (haslo) {
#pragma unroll
            for (int s = 0; s < KS; ++s)
                c = __builtin_amdgcn_mfma_f32_16x16x32_bf16(
                        a[s], *(const bf16x8v*)(bp + 2048 * KS + s * 512), c, 0, 0, 0);
        }
        acc[t] = c;
        const float sa = a_src[t * 16 + l15];
        const float sd = a_dst[t * 16 + l15];
#pragma unroll
        for (int r = 0; r < 4; ++r) {
            vsr[r] = fmaf(c[r], sa, vsr[r]);
            vdr[r] = fmaf(c[r], sd, vdr[r]);
        }
    }

#pragma unroll
    for (int r = 0; r < 4; ++r) {
        const int row = row0 + g * 4 + r;
        if (row < N_NODES) {
            unsigned short* hr = (unsigned short*)hb + (long)row * 64 + l15;
#pragma unroll
            for (int t = 0; t < 4; ++t)
                hr[t * 16] = __bfloat16_as_ushort(__float2bfloat16(acc[t][r]));
        }
    }

#pragma unroll
    for (int off = 1; off < 16; off <<= 1) {
#pragma unroll
        for (int r = 0; r < 4; ++r) {
            vsr[r] += __shfl_xor(vsr[r], off, 64);
            vdr[r] += __shfl_xor(vdr[r], off, 64);
        }
    }
    if (l15 == 0) {
#pragma unroll
        for (int r = 0; r < 4; ++r) {
            const int row = row0 + g * 4 + r;
            if (row < N_NODES) { as_out[row] = vsr[r]; ad_out[row] = vdr[r]; }
        }
    }
}

// Fused: binpass blocks first, then gemm1 blocks (MFMA when bf16 input,
// VALU fallback for fp32 input).
__global__ __launch_bounds__(256)
void gemm1_bin(const void* __restrict__ x, const float* __restrict__ W,
               const short* __restrict__ wb1,
               const float* __restrict__ a_src, const float* __restrict__ a_dst,
               const unsigned* __restrict__ flag, bf16* __restrict__ hb,
               float* __restrict__ as_out, float* __restrict__ ad_out,
               const int* __restrict__ ei, int* __restrict__ cur256,
               unsigned* __restrict__ scratch)
{
    __shared__ __align__(16) unsigned char smem[(128 * 64 + 64 * 132) * 4]; // 66560
    if (blockIdx.x < BIN_GRID) {
        binpass_body(smem, blockIdx.x, ei, cur256, scratch);
    } else if (*flag != 0u) {
        mfma_gemm_body<4>(blockIdx.x - BIN_GRID, (const unsigned short*)x,
                          wb1, a_src, a_dst, hb, as_out, ad_out, false);
    } else {
        gemm_body<128, 1>(smem, blockIdx.x - BIN_GRID, x, W, a_src, a_dst,
                          flag, hb, as_out, ad_out);
    }
}

// Standalone MFMA gemm (layers 2/3); skips zero lo-halves when bf16 params.
__global__ __launch_bounds__(256)
void gemm_mfma(const unsigned short* __restrict__ xb,
               const short* __restrict__ Wb,
               const float* __restrict__ a_src, const float* __restrict__ a_dst,
               const unsigned* __restrict__ flag,
               bf16* __restrict__ hb, float* __restrict__ as_out,
               float* __restrict__ ad_out)
{
    mfma_gemm_body<2>(blockIdx.x, xb, Wb, a_src, a_dst, hb, as_out, ad_out,
                      *flag == 0u);
}

// ---------------- GAT gather (R7-proven LDS-staged form) --------------------
#define EDGE4_FMA(wX, pX) {                                                  \
    f32x2 w2_ = { wX, wX };                                                  \
    A0 = __builtin_elementwise_fma(w2_, unpk(pX.x), A0);                     \
    A1 = __builtin_elementwise_fma(w2_, unpk(pX.y), A1);                     \
    A2 = __builtin_elementwise_fma(w2_, unpk(pX.z), A2);                     \
    A3 = __builtin_elementwise_fma(w2_, unpk(pX.w), A3); }

template<bool DO_ELU, int OMODE>
__global__ __launch_bounds__(256)
void gat_gather(const int* __restrict__ rowptr,
                const int* __restrict__ csr_src,
                const float* __restrict__ as_in,
                const float* __restrict__ ad_in,
                const unsigned short* __restrict__ hb_in,
                const float* __restrict__ bias,
                void* __restrict__ out,
                const unsigned* __restrict__ flag)
{
    __shared__ int2 s_sw[16 * 64];                 // (src, w) per slot, 8KB
    const int tid  = threadIdx.x;
    const int lane = tid & 63;
    const int l16  = lane & 15;
    const int sub  = l16 >> 3;                     // edge parity slot 0/1
    const int c8   = (l16 & 7) * 8;                // channel group
    const int grp  = tid >> 4;                     // group id in block (0..15)
    const int node = blockIdx.x * 16 + grp;        // grid exact: 3125*16=50000

    const int beg = rowptr[node];
    const int deg = rowptr[node + 1] - beg;
    const float adv = ad_in[node];
    const int nst = (deg < 64) ? deg : 64;

    for (int j = l16; j < nst; j += 16) {
        int s = csr_src[beg + j];
        float v = as_in[s] + adv;
        v = (v > 0.f) ? v : NEG_SLOPE * v;
        s_sw[grp * 64 + j] = make_int2(s, __float_as_int(__expf(fminf(v, 60.f))));
    }
    // writer wave == reader wave: lgkmcnt ordering suffices, no barrier

    f32x2 A0 = {0.f, 0.f}, A1 = {0.f, 0.f}, A2 = {0.f, 0.f}, A3 = {0.f, 0.f};
    float dsum = 0.f;

    for (int j0 = 0; j0 < deg; j0 += 8) {
        const int jA = j0 + sub,     jB = j0 + 2 + sub;
        const int jC = j0 + 4 + sub, jD = j0 + 6 + sub;
        const bool vA = jA < deg, vB = jB < deg, vC = jC < deg, vD = jD < deg;
        int sA = 0, sB = 0, sC = 0, sD = 0;
        float wA = 0.f, wB = 0.f, wC = 0.f, wD = 0.f;
        if (vA) {
            if (jA < 64) { int2 t = s_sw[grp * 64 + jA]; sA = t.x; wA = __int_as_float(t.y); }
            else { sA = csr_src[beg + jA]; float v = as_in[sA] + adv;
                   v = (v > 0.f) ? v : NEG_SLOPE * v; wA = __expf(fminf(v, 60.f)); }
        }
        if (vB) {
            if (jB < 64) { int2 t = s_sw[grp * 64 + jB]; sB = t.x; wB = __int_as_float(t.y); }
            else { sB = csr_src[beg + jB]; float v = as_in[sB] + adv;
                   v = (v > 0.f) ? v : NEG_SLOPE * v; wB = __expf(fminf(v, 60.f)); }
        }
        if (vC) {
            if (jC < 64) { int2 t = s_sw[grp * 64 + jC]; sC = t.x; wC = __int_as_float(t.y); }
            else { sC = csr_src[beg + jC]; float v = as_in[sC] + adv;
                   v = (v > 0.f) ? v : NEG_SLOPE * v; wC = __expf(fminf(v, 60.f)); }
        }
        if (vD) {
            if (jD < 64) { int2 t = s_sw[grp * 64 + jD]; sD = t.x; wD = __int_as_float(t.y); }
            else { sD = csr_src[beg + jD]; float v = as_in[sD] + adv;
                   v = (v > 0.f) ? v : NEG_SLOPE * v; wD = __expf(fminf(v, 60.f)); }
        }
        uint4 pA={0u,0u,0u,0u}, pB={0u,0u,0u,0u}, pC={0u,0u,0u,0u}, pD={0u,0u,0u,0u};
        if (vA) pA = *(const uint4*)&hb_in[(long)sA * 64 + c8];
        if (vB) pB = *(const uint4*)&hb_in[(long)sB * 64 + c8];
        if (vC) pC = *(const uint4*)&hb_in[(long)sC * 64 + c8];
        if (vD) pD = *(const uint4*)&hb_in[(long)sD * 64 + c8];
        EDGE4_FMA(wA, pA) EDGE4_FMA(wB, pB) EDGE4_FMA(wC, pC) EDGE4_FMA(wD, pD)
        dsum += (wA + wB) + (wC + wD);
    }

    float a0 = A0.x, a1 = A0.y, a2 = A1.x, a3 = A1.y;
    float a4 = A2.x, a5 = A2.y, a6 = A3.x, a7 = A3.y;
    a0 += __shfl_xor(a0, 8, 64); a1 += __shfl_xor(a1, 8, 64);
    a2 += __shfl_xor(a2, 8, 64); a3 += __shfl_xor(a3, 8, 64);
    a4 += __shfl_xor(a4, 8, 64); a5 += __shfl_xor(a5, 8, 64);
    a6 += __shfl_xor(a6, 8, 64); a7 += __shfl_xor(a7, 8, 64);
    dsum += __shfl_xor(dsum, 8, 64);

    if (sub == 0) {   // lanes l16 0..7 hold channels c8..c8+7
        float inv = 1.f / dsum;
        float r[8] = {a0, a1, a2, a3, a4, a5, a6, a7};
#pragma unroll
        for (int k = 0; k < 8; ++k) {
            r[k] = r[k] * inv + bias[c8 + k];
            if (DO_ELU) r[k] = (r[k] > 0.f) ? r[k] : expm1f(r[k]);
        }
        long o = (long)node * 64 + c8;
        bool bfst = (OMODE == 0) || (*flag != 0u);
        if (bfst) {
            uint4 u;
            u.x = ((unsigned)__bfloat16_as_ushort(__float2bfloat16(r[0]))) |
                  (((unsigned)__bfloat16_as_ushort(__float2bfloat16(r[1]))) << 16);
            u.y = ((unsigned)__bfloat16_as_ushort(__float2bfloat16(r[2]))) |
                  (((unsigned)__bfloat16_as_ushort(__float2bfloat16(r[3]))) << 16);
            u.z = ((unsigned)__bfloat16_as_ushort(__float2bfloat16(r[4]))) |
                  (((unsigned)__bfloat16_as_ushort(__float2bfloat16(r[5]))) << 16);
            u.w = ((unsigned)__bfloat16_as_ushort(__float2bfloat16(r[6]))) |
                  (((unsigned)__bfloat16_as_ushort(__float2bfloat16(r[7]))) << 16);
            *(uint4*)&((unsigned short*)out)[o] = u;
        } else {
            float4 f0 = {r[0], r[1], r[2], r[3]};
            float4 f1 = {r[4], r[5], r[6], r[7]};
            *(float4*)&((float*)out)[o]     = f0;
            *(float4*)&((float*)out)[o + 4] = f1;
        }
    }
}

extern "C" void kernel_launch(void* const* d_in, const int* in_sizes, int n_in,
                              void* d_out, int out_size, void* d_ws, size_t ws_size,
                              hipStream_t stream)
{
    const void* x  = d_in[0];
    const int*  ei = (const int*)d_in[1];
    const void* pW1 = d_in[2],  *pas1 = d_in[3],  *pad1 = d_in[4],  *pb1 = d_in[5];
    const void* pW2 = d_in[6],  *pas2 = d_in[7],  *pad2 = d_in[8],  *pb2 = d_in[9];
    const void* pW3 = d_in[10], *pas3 = d_in[11], *pad3 = d_in[12], *pb3 = d_in[13];

    float* ws = (float*)d_ws;
    bf16*     hbA    = (bf16*)ws;                              // 6.4 MB
    bf16*     hbB    = (bf16*)(ws + (long)N_NODES * 32);       // 6.4 MB
    float*    as_    = ws + (long)N_NODES * 64;
    float*    ad_    = as_ + N_NODES;
    int*      cur256 = (int*)(ad_ + N_NODES);                  // NBUCK
    int*      rowptr = cur256 + NBUCK;                         // N+1
    int*      csr_src= rowptr + N_NODES + 1;                   // 3.4 MB
    unsigned* scratch= (unsigned*)(csr_src + ET_EDGES);        // NBUCK*CAP 6.4 MB
    float*    prm    = (float*)(scratch + (long)NBUCK * CAP);
    unsigned* flag   = (unsigned*)(prm + 20000);
    short*    wb2    = (short*)(prm + 20008);                  // 8192 shorts (hi+lo)
    short*    wb3    = wb2 + 8192;                             // 8192 shorts
    short*    wb1    = wb3 + 8192;                             // 16384 shorts (hi)

    float* W1 = prm;     float* as1 = W1 + 8192; float* ad1 = as1 + 64; float* b1 = ad1 + 64;
    float* W2 = b1 + 64; float* as2 = W2 + 4096; float* ad2 = as2 + 64; float* b2 = ad2 + 64;
    float* W3 = b2 + 64; float* as3 = W3 + 4096; float* ad3 = as3 + 64; float* b3 = ad3 + 64;

    PrepArgs pa;
    const void* srcs[12] = {pW1, pas1, pad1, pb1, pW2, pas2, pad2, pb2, pW3, pas3, pad3, pb3};
    float*      dsts[12] = {W1, as1, ad1, b1, W2, as2, ad2, b2, W3, as3, ad3, b3};
    int         ns[12]   = {8192, 64, 64, 64, 4096, 64, 64, 64, 4096, 64, 64, 64};
    for (int i = 0; i < 12; ++i) { pa.src[i] = srcs[i]; pa.dst[i] = dsts[i]; pa.n[i] = ns[i]; }
    prep<<<dim3(8, 16), 256, 0, stream>>>(
        pa, (const unsigned short*)pW1, pW2, pW3, wb1, wb2, wb3, flag, cur256);

    const int gat_grid = GAT_GRID;   // 3125, exact

    // ---------- Layer 1 GEMM (MFMA when bf16) fused with CSR binpass --------
    gemm1_bin<<<BIN_GRID + GEMM_GRID, 256, 0, stream>>>(
        x, W1, wb1, as1, ad1, flag, hbA, as_, ad_, ei, cur256, scratch);
    fine_scatter<<<NBUCK, 256, 0, stream>>>(cur256, scratch, csr_src, rowptr);
    gat_gather<true, 0><<<gat_grid, 256, 0, stream>>>(
        rowptr, csr_src, as_, ad_, (const unsigned short*)hbA, b1, hbB, flag);

    // ---------- Layer 2 (bf16 MFMA gemm) ----------
    gemm_mfma<<<GEMM_GRID, 256, 0, stream>>>(
        (const unsigned short*)hbB, wb2, as2, ad2, flag, hbA, as_, ad_);
    gat_gather<true, 0><<<gat_grid, 256, 0, stream>>>(
        rowptr, csr_src, as_, ad_, (const unsigned short*)hbA, b2, hbB, flag);

    // ---------- Layer 3 (bf16 MFMA gemm) ----------
    gemm_mfma<<<GEMM_GRID, 256, 0, stream>>>(
        (const unsigned short*)hbB, wb3, as3, ad3, flag, hbA, as_, ad_);
    gat_gather<false, 1><<<gat_grid, 256, 0, stream>>>(
        rowptr, csr_src, as_, ad_, (const unsigned short*)hbA, b3, d_out, flag);
}

// Round 12
// 204.961 us; speedup vs baseline: 1.1054x; 1.1054x over previous
//
#include <hip/hip_runtime.h>
#include <hip/hip_bf16.h>
#include <math.h>

#define N_NODES 50000
#define N_EDGES 800000
#define ET_EDGES (N_EDGES + N_NODES)   // with self-loops
#define NEG_SLOPE 0.2f
#define NBUCK ((N_NODES + 255) / 256)  // 196 dst buckets (256 nodes each)
#define CHUNK 4096                      // edges per binning block
#define CAP   8192                      // scratch slots per bucket (>50 sigma)
#define BIN_GRID ((ET_EDGES + CHUNK - 1) / CHUNK)   // 208
#define GEMM_GRID ((N_NODES + 63) / 64)             // 782
#define GAT_GRID (N_NODES / 16)                     // 3125 exact
#define G1_SMEM 20608                   // max(binpass 20548, f32-fallback 17408)

typedef __hip_bfloat16 bf16;
typedef float f32x2 __attribute__((ext_vector_type(2)));
typedef __attribute__((ext_vector_type(8))) short bf16x8v;  // MFMA A/B frag
typedef __attribute__((ext_vector_type(4))) float f32x4v;   // MFMA C/D frag

__device__ inline float bfbits(unsigned short u) {
    return __uint_as_float(((unsigned)u) << 16);
}
__device__ inline float bflo(unsigned u) { return __uint_as_float(u << 16); }
__device__ inline float bfhi(unsigned u) { return __uint_as_float(u & 0xffff0000u); }
__device__ inline f32x2 unpk(unsigned u) {
    f32x2 r; r.x = bflo(u); r.y = bfhi(u); return r;
}
__device__ inline f32x2 bcast2(float v) { f32x2 r; r.x = v; r.y = v; return r; }

// ---------------- prep: params + cursors + flag + MFMA-packed W1/W2/W3 ------
// (unchanged from R11)
struct PrepArgs {
    const void* src[12];
    float*      dst[12];
    int         n[12];
};

__global__ __launch_bounds__(256)
void prep(PrepArgs a, const unsigned short* __restrict__ w1raw,
          const void* __restrict__ w2raw, const void* __restrict__ w3raw,
          short* __restrict__ wb1, short* __restrict__ wb2,
          short* __restrict__ wb3,
          unsigned* __restrict__ flag, int* __restrict__ cur256)
{
    __shared__ unsigned sflag;
    const int tid = threadIdx.x;
    if (tid < 64) {
        float v0 = bfbits(w1raw[2 * tid]);
        float v1 = bfbits(w1raw[2 * tid + 1]);
        bool bad = !(fabsf(v0) <= 64.f && fabsf(v1) <= 64.f);  // NaN -> bad
        unsigned long long b = __ballot(bad);
        if (tid == 0) sflag = (b == 0ull) ? 1u : 0u;
    }
    __syncthreads();
    const bool isbf = (sflag != 0u);
    const int which = blockIdx.y;

    if (which == 12) {
        int i = blockIdx.x * 256 + tid;
        if (i < NBUCK) cur256[i] = i * CAP;
        if (blockIdx.x == 0 && tid == 0) *flag = isbf ? 1u : 0u;
        return;
    }
    if (which == 13 || which == 14) {
        const void* praw = (which == 13) ? w2raw : w3raw;
        short* dstp = (which == 13) ? wb2 : wb3;
        for (int idx = blockIdx.x * 256 + tid; idx < 4096; idx += 8 * 256) {
            const int i  = idx & 7;
            const int ln = (idx >> 3) & 63;
            const int ts = idx >> 9;            // 0..7 (t*2+s)
            const int t  = ts >> 1, s = ts & 1;
            const int k   = s * 32 + (ln >> 4) * 8 + i;
            const int col = t * 16 + (ln & 15);
            float wv = isbf ? bfbits(((const unsigned short*)praw)[k * 64 + col])
                            : ((const float*)praw)[k * 64 + col];
            bf16 hi = __float2bfloat16(wv);
            float lof = wv - __bfloat162float(hi);
            dstp[idx]        = (short)__bfloat16_as_ushort(hi);
            dstp[4096 + idx] = (short)__bfloat16_as_ushort(__float2bfloat16(lof));
        }
        return;
    }
    if (which == 15) {       // W1 pack, KS=4, hi only (exact when bf16 input)
        for (int idx = blockIdx.x * 256 + tid; idx < 16384; idx += 8 * 256) {
            const int i  = idx & 7;
            const int ln = (idx >> 3) & 63;
            const int ts = idx >> 9;            // 0..31 (t*4+s)
            const int t  = ts >> 2, s = ts & 3;
            const int k   = s * 32 + (ln >> 4) * 8 + i;   // k < 128
            const int col = t * 16 + (ln & 15);
            float wv = isbf ? bfbits(w1raw[k * 64 + col])
                            : ((const float*)w1raw)[k * 64 + col];
            wb1[idx] = (short)__bfloat16_as_ushort(__float2bfloat16(wv));
        }
        return;
    }
    const int n = a.n[which];
    const void* s = a.src[which];
    float* d = a.dst[which];
    for (int i = blockIdx.x * 256 + tid; i < n; i += 8 * 256)
        d[i] = isbf ? bfbits(((const unsigned short*)s)[i])
                    : ((const float*)s)[i];
}

// ---------------- binpass body (fused with gemm1) ---------------------------
__device__ void binpass_body(unsigned char* smem, int bid,
                             const int* __restrict__ ei,
                             int* __restrict__ cur256,
                             unsigned* __restrict__ scratch)
{
    int* hist   = (int*)smem;                  // 196
    int* lpre   = hist + NBUCK;                // 197
    int* lcur   = lpre + NBUCK + 1;            // 196
    int* gbase  = lcur + NBUCK;                // 196
    int* scan_a = gbase + NBUCK;               // 256
    unsigned* entry = (unsigned*)(scan_a + 256); // 4096

    const int tid = threadIdx.x;
    const int e0  = bid * CHUNK;
    const int n   = min(CHUNK, ET_EDGES - e0);

    if (tid < NBUCK) hist[tid] = 0;
    __syncthreads();

    for (int k = tid; k < n; k += 256) {
        int e = e0 + k;
        int d = (e < N_EDGES) ? ei[N_EDGES + e] : e - N_EDGES;
        atomicAdd(&hist[d >> 8], 1);
    }
    __syncthreads();

    int v = (tid < NBUCK) ? hist[tid] : 0;
    scan_a[tid] = v;
    __syncthreads();
    for (int off = 1; off < 256; off <<= 1) {
        int t = (tid >= off) ? scan_a[tid - off] : 0;
        __syncthreads();
        scan_a[tid] += t;
        __syncthreads();
    }
    if (tid < NBUCK) lpre[tid] = scan_a[tid] - v;
    if (tid == NBUCK - 1) lpre[NBUCK] = scan_a[tid];
    if (tid < NBUCK) {
        gbase[tid] = v ? atomicAdd(&cur256[tid], v) : 0;
        lcur[tid] = 0;
    }
    __syncthreads();

    for (int k = tid; k < n; k += 256) {
        int e = e0 + k;
        int s, d;
        if (e < N_EDGES) { s = ei[e]; d = ei[N_EDGES + e]; }
        else             { s = d = e - N_EDGES; }
        int b = d >> 8;
        int p = atomicAdd(&lcur[b], 1);
        entry[lpre[b] + p] = ((unsigned)s << 8) | (unsigned)(d & 255);
    }
    __syncthreads();

    for (int i = tid; i < n; i += 256) {
        int lo = 0, hi = NBUCK;
        while (hi - lo > 1) {
            int mid = (lo + hi) >> 1;
            if (lpre[mid] <= i) lo = mid; else hi = mid;
        }
        scratch[gbase[lo] + (i - lpre[lo])] = entry[i];
    }
}

// ---------------- fine_scatter (standalone, R5-proven) ----------------------
__global__ __launch_bounds__(256)
void fine_scatter(const int* __restrict__ cur256,
                  const unsigned* __restrict__ scratch,
                  int* __restrict__ csr_src,
                  int* __restrict__ rowptr)
{
    __shared__ int scnt[256];
    __shared__ int cnt[256];
    __shared__ int pre[256];
    const int tid = threadIdx.x;
    const int b   = blockIdx.x;
    const int nb  = b * 256;
    const int nn  = min(256, N_NODES - nb);

    int bv = (tid < NBUCK) ? (cur256[tid] - tid * CAP) : 0;
    scnt[tid] = bv;
    __syncthreads();
    for (int off = 1; off < 256; off <<= 1) {
        int u = (tid >= off) ? scnt[tid - off] : 0;
        __syncthreads();
        scnt[tid] += u;
        __syncthreads();
    }
    const int gb = scnt[b] - (cur256[b] - b * CAP);   // exclusive prefix at b
    const int n  = cur256[b] - b * CAP;               // realized count
    const long seg = (long)b * CAP;

    cnt[tid] = 0;
    __syncthreads();
    for (int i = tid; i < n; i += 256)
        atomicAdd(&cnt[scratch[seg + i] & 255u], 1);
    __syncthreads();

    int v = cnt[tid];
    pre[tid] = v;
    __syncthreads();
    for (int off = 1; off < 256; off <<= 1) {
        int t = (tid >= off) ? pre[tid - off] : 0;
        __syncthreads();
        pre[tid] += t;
        __syncthreads();
    }
    int excl = pre[tid] - v + gb;
    if (tid < nn) rowptr[nb + tid] = excl;
    if (b == NBUCK - 1 && tid == 0) rowptr[N_NODES] = ET_EDGES;
    cnt[tid] = excl;    // reuse as cursors
    __syncthreads();

    for (int i = tid; i < n; i += 256) {
        unsigned e = scratch[seg + i];
        int p = atomicAdd(&cnt[e & 255u], 1);
        csr_src[p] = (int)(e >> 8);
    }
}

// ---------------- GEMM1 fp32 fallback (k-chunked, fits 20.6KB arena) --------
// R12: 32-wide k chunks (sW 8KB + sx 64x36 9.2KB = 17.4KB). Structure = R8's
// k-split gemm (field-proven); only taken for fp32 inputs.
template<int CIN>
__device__ void gemm_body_f32(unsigned char* smem, int bid,
                              const float* __restrict__ xf,
                              const float* __restrict__ W,
                              const float* __restrict__ a_src,
                              const float* __restrict__ a_dst,
                              bf16* __restrict__ hb,
                              float* __restrict__ as_out,
                              float* __restrict__ ad_out)
{
    float* sW = (float*)smem;                 // [32][64]
    float* sx = sW + 32 * 64;                 // [64][36] padded
    const int tid  = threadIdx.x;
    const int colg = tid & 15;
    const int rowg = tid >> 4;
    const int c0   = colg * 4;
    const int r0l  = rowg * 4;
    const int row0 = bid * 64;

    f32x2 acc[4][2];
#pragma unroll
    for (int r = 0; r < 4; ++r) {
        acc[r][0] = (f32x2){0.f, 0.f};
        acc[r][1] = (f32x2){0.f, 0.f};
    }

    for (int k0 = 0; k0 < CIN; k0 += 32) {
        __syncthreads();
        for (int i = tid * 4; i < 2048; i += 1024)
            *(float4*)&sW[i] = *(const float4*)&W[k0 * 64 + i];
        for (int i = tid * 4; i < 2048; i += 1024) {
            const int r = i >> 5, k = i & 31;
            float4 v = {0.f, 0.f, 0.f, 0.f};
            if (row0 + r < N_NODES)
                v = *(const float4*)&xf[(long)(row0 + r) * CIN + k0 + k];
            *(float4*)&sx[r * 36 + k] = v;
        }
        __syncthreads();

#pragma unroll 2
        for (int kk = 0; kk < 32; kk += 4) {
            const float4 w0 = *(const float4*)&sW[(kk + 0) * 64 + c0];
            const float4 w1 = *(const float4*)&sW[(kk + 1) * 64 + c0];
            const float4 w2 = *(const float4*)&sW[(kk + 2) * 64 + c0];
            const float4 w3 = *(const float4*)&sW[(kk + 3) * 64 + c0];
            f32x2 w0lo; w0lo.x = w0.x; w0lo.y = w0.y;
            f32x2 w0hi; w0hi.x = w0.z; w0hi.y = w0.w;
            f32x2 w1lo; w1lo.x = w1.x; w1lo.y = w1.y;
            f32x2 w1hi; w1hi.x = w1.z; w1hi.y = w1.w;
            f32x2 w2lo; w2lo.x = w2.x; w2lo.y = w2.y;
            f32x2 w2hi; w2hi.x = w2.z; w2hi.y = w2.w;
            f32x2 w3lo; w3lo.x = w3.x; w3lo.y = w3.y;
            f32x2 w3hi; w3hi.x = w3.z; w3hi.y = w3.w;
#pragma unroll
            for (int r = 0; r < 4; ++r) {
                const float4 xv = *(const float4*)&sx[(r0l + r) * 36 + kk];
                acc[r][0] = __builtin_elementwise_fma(bcast2(xv.x), w0lo, acc[r][0]);
                acc[r][1] = __builtin_elementwise_fma(bcast2(xv.x), w0hi, acc[r][1]);
                acc[r][0] = __builtin_elementwise_fma(bcast2(xv.y), w1lo, acc[r][0]);
                acc[r][1] = __builtin_elementwise_fma(bcast2(xv.y), w1hi, acc[r][1]);
                acc[r][0] = __builtin_elementwise_fma(bcast2(xv.z), w2lo, acc[r][0]);
                acc[r][1] = __builtin_elementwise_fma(bcast2(xv.z), w2hi, acc[r][1]);
                acc[r][0] = __builtin_elementwise_fma(bcast2(xv.w), w3lo, acc[r][0]);
                acc[r][1] = __builtin_elementwise_fma(bcast2(xv.w), w3hi, acc[r][1]);
            }
        }
    }

    const float4 sa4 = *(const float4*)&a_src[c0];
    const float4 sd4 = *(const float4*)&a_dst[c0];
#pragma unroll
    for (int r = 0; r < 4; ++r) {
        const int row = row0 + r0l + r;
        const float h0 = acc[r][0].x, h1 = acc[r][0].y;
        const float h2 = acc[r][1].x, h3 = acc[r][1].y;
        float vs = fmaf(h0, sa4.x, fmaf(h1, sa4.y, fmaf(h2, sa4.z, h3 * sa4.w)));
        float vd = fmaf(h0, sd4.x, fmaf(h1, sd4.y, fmaf(h2, sd4.z, h3 * sd4.w)));
#pragma unroll
        for (int off = 1; off < 16; off <<= 1) {
            vs += __shfl_xor(vs, off, 64);
            vd += __shfl_xor(vd, off, 64);
        }
        if (row < N_NODES) {
            uint2 u;
            u.x = ((unsigned)__bfloat16_as_ushort(__float2bfloat16(h0))) |
                  (((unsigned)__bfloat16_as_ushort(__float2bfloat16(h1))) << 16);
            u.y = ((unsigned)__bfloat16_as_ushort(__float2bfloat16(h2))) |
                  (((unsigned)__bfloat16_as_ushort(__float2bfloat16(h3))) << 16);
            *(uint2*)&((unsigned short*)hb)[(long)row * 64 + c0] = u;
            if (colg == 0) { as_out[row] = vs; ad_out[row] = vd; }
        }
    }
}

// ---------------- bf16 MFMA gemm body (R10/R11-proven) ----------------------
template<int KS>
__device__ void mfma_gemm_body(int bid,
                               const unsigned short* __restrict__ xb,
                               const short* __restrict__ Wb,
                               const float* __restrict__ a_src,
                               const float* __restrict__ a_dst,
                               bf16* __restrict__ hb,
                               float* __restrict__ as_out,
                               float* __restrict__ ad_out,
                               bool haslo)
{
    constexpr int CIN = KS * 32;
    const int tid  = threadIdx.x;
    const int lane = tid & 63;
    const int wv_  = tid >> 6;
    const int g    = lane >> 4;
    const int l15  = lane & 15;
    const int row0 = bid * 64 + wv_ * 16;

    const int ar = row0 + l15;
    const long abase = (long)((ar < N_NODES) ? ar : 0) * CIN + g * 8;
    bf16x8v a[KS];
#pragma unroll
    for (int s = 0; s < KS; ++s)
        a[s] = *(const bf16x8v*)&xb[abase + s * 32];

    f32x4v acc[4];
    float vsr[4] = {0.f, 0.f, 0.f, 0.f};
    float vdr[4] = {0.f, 0.f, 0.f, 0.f};
#pragma unroll
    for (int t = 0; t < 4; ++t) {
        const short* bp = &Wb[(t * KS) * 512 + lane * 8];
        f32x4v c = {0.f, 0.f, 0.f, 0.f};
#pragma unroll
        for (int s = 0; s < KS; ++s)
            c = __builtin_amdgcn_mfma_f32_16x16x32_bf16(
                    a[s], *(const bf16x8v*)(bp + s * 512), c, 0, 0, 0);
        if (haslo) {
#pragma unroll
            for (int s = 0; s < KS; ++s)
                c = __builtin_amdgcn_mfma_f32_16x16x32_bf16(
                        a[s], *(const bf16x8v*)(bp + 2048 * KS + s * 512), c, 0, 0, 0);
        }
        acc[t] = c;
        const float sa = a_src[t * 16 + l15];
        const float sd = a_dst[t * 16 + l15];
#pragma unroll
        for (int r = 0; r < 4; ++r) {
            vsr[r] = fmaf(c[r], sa, vsr[r]);
            vdr[r] = fmaf(c[r], sd, vdr[r]);
        }
    }

#pragma unroll
    for (int r = 0; r < 4; ++r) {
        const int row = row0 + g * 4 + r;
        if (row < N_NODES) {
            unsigned short* hr = (unsigned short*)hb + (long)row * 64 + l15;
#pragma unroll
            for (int t = 0; t < 4; ++t)
                hr[t * 16] = __bfloat16_as_ushort(__float2bfloat16(acc[t][r]));
        }
    }

#pragma unroll
    for (int off = 1; off < 16; off <<= 1) {
#pragma unroll
        for (int r = 0; r < 4; ++r) {
            vsr[r] += __shfl_xor(vsr[r], off, 64);
            vdr[r] += __shfl_xor(vdr[r], off, 64);
        }
    }
    if (l15 == 0) {
#pragma unroll
        for (int r = 0; r < 4; ++r) {
            const int row = row0 + g * 4 + r;
            if (row < N_NODES) { as_out[row] = vsr[r]; ad_out[row] = vdr[r]; }
        }
    }
}

// Fused: binpass blocks first, then gemm1 blocks.
// R12: static LDS shrunk 66.5KB -> 20.6KB (binpass size); fp32 fallback is
// now k-chunked. MFMA path uses no LDS. Occupancy 2 -> ~5-7 blocks/CU.
__global__ __launch_bounds__(256)
void gemm1_bin(const void* __restrict__ x, const float* __restrict__ W,
               const short* __restrict__ wb1,
               const float* __restrict__ a_src, const float* __restrict__ a_dst,
               const unsigned* __restrict__ flag, bf16* __restrict__ hb,
               float* __restrict__ as_out, float* __restrict__ ad_out,
               const int* __restrict__ ei, int* __restrict__ cur256,
               unsigned* __restrict__ scratch)
{
    __shared__ __align__(16) unsigned char smem[G1_SMEM];
    if (blockIdx.x < BIN_GRID) {
        binpass_body(smem, blockIdx.x, ei, cur256, scratch);
    } else if (*flag != 0u) {
        mfma_gemm_body<4>(blockIdx.x - BIN_GRID, (const unsigned short*)x,
                          wb1, a_src, a_dst, hb, as_out, ad_out, false);
    } else {
        gemm_body_f32<128>(smem, blockIdx.x - BIN_GRID, (const float*)x, W,
                           a_src, a_dst, hb, as_out, ad_out);
    }
}

// ---------------- fused GAT gather + next-layer MFMA gemm -------------------
// R12: a gather block's 16 nodes are exactly one 16x64 MFMA A-tile. Phase 1 =
// R7-proven gat body writing the post-ELU row to a 2KB LDS tile; barrier;
// wave 0 computes h_next = tile x W_next (R10-proven MFMA body, A from LDS)
// and writes hb_out + next-layer alphas. Removes hbB roundtrip + 1 dispatch.
#define EDGE4_FMA(wX, pX) {                                                  \
    f32x2 w2_ = { wX, wX };                                                  \
    A0 = __builtin_elementwise_fma(w2_, unpk(pX.x), A0);                     \
    A1 = __builtin_elementwise_fma(w2_, unpk(pX.y), A1);                     \
    A2 = __builtin_elementwise_fma(w2_, unpk(pX.z), A2);                     \
    A3 = __builtin_elementwise_fma(w2_, unpk(pX.w), A3); }

__global__ __launch_bounds__(256)
void gat_gemm(const int* __restrict__ rowptr,
              const int* __restrict__ csr_src,
              const float* __restrict__ as_in,   // alphas of this layer
              const float* __restrict__ ad_in,
              const unsigned short* __restrict__ hb_in,
              const float* __restrict__ bias,    // this layer's bias
              const short* __restrict__ Wb_next, // packed next-layer W (KS=2)
              const float* __restrict__ asn,     // next-layer a_src
              const float* __restrict__ adn,     // next-layer a_dst
              const unsigned* __restrict__ flag,
              bf16* __restrict__ hb_out,         // next-layer h
              float* __restrict__ as_out,        // next-layer alphas
              float* __restrict__ ad_out)
{
    __shared__ int2 s_sw[16 * 64];                 // (src, w) per slot, 8KB
    __shared__ unsigned short s_tile[16 * 64];     // post-ELU tile, 2KB
    const int tid  = threadIdx.x;
    const int lane = tid & 63;
    const int wv_  = tid >> 6;
    const int l16  = lane & 15;
    const int sub  = l16 >> 3;                     // edge parity slot 0/1
    const int c8   = (l16 & 7) * 8;                // channel group
    const int grp  = tid >> 4;                     // group id in block (0..15)
    const int node = blockIdx.x * 16 + grp;        // grid exact: 3125*16=50000

    const int beg = rowptr[node];
    const int deg = rowptr[node + 1] - beg;
    const float adv = ad_in[node];
    const int nst = (deg < 64) ? deg : 64;

    for (int j = l16; j < nst; j += 16) {
        int s = csr_src[beg + j];
        float v = as_in[s] + adv;
        v = (v > 0.f) ? v : NEG_SLOPE * v;
        s_sw[grp * 64 + j] = make_int2(s, __float_as_int(__expf(fminf(v, 60.f))));
    }
    // writer wave == reader wave: lgkmcnt ordering suffices, no barrier

    f32x2 A0 = {0.f, 0.f}, A1 = {0.f, 0.f}, A2 = {0.f, 0.f}, A3 = {0.f, 0.f};
    float dsum = 0.f;

    for (int j0 = 0; j0 < deg; j0 += 8) {
        const int jA = j0 + sub,     jB = j0 + 2 + sub;
        const int jC = j0 + 4 + sub, jD = j0 + 6 + sub;
        const bool vA = jA < deg, vB = jB < deg, vC = jC < deg, vD = jD < deg;
        int sA = 0, sB = 0, sC = 0, sD = 0;
        float wA = 0.f, wB = 0.f, wC = 0.f, wD = 0.f;
        if (vA) {
            if (jA < 64) { int2 t = s_sw[grp * 64 + jA]; sA = t.x; wA = __int_as_float(t.y); }
            else { sA = csr_src[beg + jA]; float v = as_in[sA] + adv;
                   v = (v > 0.f) ? v : NEG_SLOPE * v; wA = __expf(fminf(v, 60.f)); }
        }
        if (vB) {
            if (jB < 64) { int2 t = s_sw[grp * 64 + jB]; sB = t.x; wB = __int_as_float(t.y); }
            else { sB = csr_src[beg + jB]; float v = as_in[sB] + adv;
                   v = (v > 0.f) ? v : NEG_SLOPE * v; wB = __expf(fminf(v, 60.f)); }
        }
        if (vC) {
            if (jC < 64) { int2 t = s_sw[grp * 64 + jC]; sC = t.x; wC = __int_as_float(t.y); }
            else { sC = csr_src[beg + jC]; float v = as_in[sC] + adv;
                   v = (v > 0.f) ? v : NEG_SLOPE * v; wC = __expf(fminf(v, 60.f)); }
        }
        if (vD) {
            if (jD < 64) { int2 t = s_sw[grp * 64 + jD]; sD = t.x; wD = __int_as_float(t.y); }
            else { sD = csr_src[beg + jD]; float v = as_in[sD] + adv;
                   v = (v > 0.f) ? v : NEG_SLOPE * v; wD = __expf(fminf(v, 60.f)); }
        }
        uint4 pA={0u,0u,0u,0u}, pB={0u,0u,0u,0u}, pC={0u,0u,0u,0u}, pD={0u,0u,0u,0u};
        if (vA) pA = *(const uint4*)&hb_in[(long)sA * 64 + c8];
        if (vB) pB = *(const uint4*)&hb_in[(long)sB * 64 + c8];
        if (vC) pC = *(const uint4*)&hb_in[(long)sC * 64 + c8];
        if (vD) pD = *(const uint4*)&hb_in[(long)sD * 64 + c8];
        EDGE4_FMA(wA, pA) EDGE4_FMA(wB, pB) EDGE4_FMA(wC, pC) EDGE4_FMA(wD, pD)
        dsum += (wA + wB) + (wC + wD);
    }

    float a0 = A0.x, a1 = A0.y, a2 = A1.x, a3 = A1.y;
    float a4 = A2.x, a5 = A2.y, a6 = A3.x, a7 = A3.y;
    a0 += __shfl_xor(a0, 8, 64); a1 += __shfl_xor(a1, 8, 64);
    a2 += __shfl_xor(a2, 8, 64); a3 += __shfl_xor(a3, 8, 64);
    a4 += __shfl_xor(a4, 8, 64); a5 += __shfl_xor(a5, 8, 64);
    a6 += __shfl_xor(a6, 8, 64); a7 += __shfl_xor(a7, 8, 64);
    dsum += __shfl_xor(dsum, 8, 64);

    if (sub == 0) {   // lanes l16 0..7 hold channels c8..c8+7 -> LDS tile
        float inv = 1.f / dsum;
        float r[8] = {a0, a1, a2, a3, a4, a5, a6, a7};
#pragma unroll
        for (int k = 0; k < 8; ++k) {
            r[k] = r[k] * inv + bias[c8 + k];
            r[k] = (r[k] > 0.f) ? r[k] : expm1f(r[k]);   // ELU (internal layers)
        }
        uint4 u;
        u.x = ((unsigned)__bfloat16_as_ushort(__float2bfloat16(r[0]))) |
              (((unsigned)__bfloat16_as_ushort(__float2bfloat16(r[1]))) << 16);
        u.y = ((unsigned)__bfloat16_as_ushort(__float2bfloat16(r[2]))) |
              (((unsigned)__bfloat16_as_ushort(__float2bfloat16(r[3]))) << 16);
        u.z = ((unsigned)__bfloat16_as_ushort(__float2bfloat16(r[4]))) |
              (((unsigned)__bfloat16_as_ushort(__float2bfloat16(r[5]))) << 16);
        u.w = ((unsigned)__bfloat16_as_ushort(__float2bfloat16(r[6]))) |
              (((unsigned)__bfloat16_as_ushort(__float2bfloat16(r[7]))) << 16);
        *(uint4*)&s_tile[grp * 64 + c8] = u;
    }
    __syncthreads();
    if (wv_ != 0) return;

    // ---- phase 2 (wave 0): 16x64 MFMA gemm on the tile ----
    const int g   = lane >> 4;
    const int l15 = lane & 15;
    const int row0 = blockIdx.x * 16;
    const bool haslo = (*flag == 0u);

    bf16x8v av0 = *(const bf16x8v*)&s_tile[l15 * 64 + g * 8];        // k 0..31
    bf16x8v av1 = *(const bf16x8v*)&s_tile[l15 * 64 + 32 + g * 8];   // k 32..63

    f32x4v acc[4];
    float vsr[4] = {0.f, 0.f, 0.f, 0.f};
    float vdr[4] = {0.f, 0.f, 0.f, 0.f};
#pragma unroll
    for (int t = 0; t < 4; ++t) {
        const short* bp = &Wb_next[t * 1024 + lane * 8];
        f32x4v c = {0.f, 0.f, 0.f, 0.f};
        c = __builtin_amdgcn_mfma_f32_16x16x32_bf16(av0, *(const bf16x8v*)bp, c, 0, 0, 0);
        c = __builtin_amdgcn_mfma_f32_16x16x32_bf16(av1, *(const bf16x8v*)(bp + 512), c, 0, 0, 0);
        if (haslo) {
            c = __builtin_amdgcn_mfma_f32_16x16x32_bf16(av0, *(const bf16x8v*)(bp + 4096), c, 0, 0, 0);
            c = __builtin_amdgcn_mfma_f32_16x16x32_bf16(av1, *(const bf16x8v*)(bp + 4608), c, 0, 0, 0);
        }
        acc[t] = c;
        const float sa = asn[t * 16 + l15];
        const float sd = adn[t * 16 + l15];
#pragma unroll
        for (int r = 0; r < 4; ++r) {
            vsr[r] = fmaf(c[r], sa, vsr[r]);
            vdr[r] = fmaf(c[r], sd, vdr[r]);
        }
    }

#pragma unroll
    for (int r = 0; r < 4; ++r) {
        const int row = row0 + g * 4 + r;
        unsigned short* hr = (unsigned short*)hb_out + (long)row * 64 + l15;
#pragma unroll
        for (int t = 0; t < 4; ++t)
            hr[t * 16] = __bfloat16_as_ushort(__float2bfloat16(acc[t][r]));
    }

#pragma unroll
    for (int off = 1; off < 16; off <<= 1) {
#pragma unroll
        for (int r = 0; r < 4; ++r) {
            vsr[r] += __shfl_xor(vsr[r], off, 64);
            vdr[r] += __shfl_xor(vdr[r], off, 64);
        }
    }
    if (l15 == 0) {
#pragma unroll
        for (int r = 0; r < 4; ++r) {
            const int row = row0 + g * 4 + r;
            as_out[row] = vsr[r];
            ad_out[row] = vdr[r];
        }
    }
}

// ---------------- GAT gather standalone (layer 3, R7-proven) ----------------
template<bool DO_ELU, int OMODE>
__global__ __launch_bounds__(256)
void gat_gather(const int* __restrict__ rowptr,
                const int* __restrict__ csr_src,
                const float* __restrict__ as_in,
                const float* __restrict__ ad_in,
                const unsigned short* __restrict__ hb_in,
                const float* __restrict__ bias,
                void* __restrict__ out,
                const unsigned* __restrict__ flag)
{
    __shared__ int2 s_sw[16 * 64];                 // (src, w) per slot, 8KB
    const int tid  = threadIdx.x;
    const int lane = tid & 63;
    const int l16  = lane & 15;
    const int sub  = l16 >> 3;                     // edge parity slot 0/1
    const int c8   = (l16 & 7) * 8;                // channel group
    const int grp  = tid >> 4;                     // group id in block (0..15)
    const int node = blockIdx.x * 16 + grp;        // grid exact: 3125*16=50000

    const int beg = rowptr[node];
    const int deg = rowptr[node + 1] - beg;
    const float adv = ad_in[node];
    const int nst = (deg < 64) ? deg : 64;

    for (int j = l16; j < nst; j += 16) {
        int s = csr_src[beg + j];
        float v = as_in[s] + adv;
        v = (v > 0.f) ? v : NEG_SLOPE * v;
        s_sw[grp * 64 + j] = make_int2(s, __float_as_int(__expf(fminf(v, 60.f))));
    }
    // writer wave == reader wave: lgkmcnt ordering suffices, no barrier

    f32x2 A0 = {0.f, 0.f}, A1 = {0.f, 0.f}, A2 = {0.f, 0.f}, A3 = {0.f, 0.f};
    float dsum = 0.f;

    for (int j0 = 0; j0 < deg; j0 += 8) {
        const int jA = j0 + sub,     jB = j0 + 2 + sub;
        const int jC = j0 + 4 + sub, jD = j0 + 6 + sub;
        const bool vA = jA < deg, vB = jB < deg, vC = jC < deg, vD = jD < deg;
        int sA = 0, sB = 0, sC = 0, sD = 0;
        float wA = 0.f, wB = 0.f, wC = 0.f, wD = 0.f;
        if (vA) {
            if (jA < 64) { int2 t = s_sw[grp * 64 + jA]; sA = t.x; wA = __int_as_float(t.y); }
            else { sA = csr_src[beg + jA]; float v = as_in[sA] + adv;
                   v = (v > 0.f) ? v : NEG_SLOPE * v; wA = __expf(fminf(v, 60.f)); }
        }
        if (vB) {
            if (jB < 64) { int2 t = s_sw[grp * 64 + jB]; sB = t.x; wB = __int_as_float(t.y); }
            else { sB = csr_src[beg + jB]; float v = as_in[sB] + adv;
                   v = (v > 0.f) ? v : NEG_SLOPE * v; wB = __expf(fminf(v, 60.f)); }
        }
        if (vC) {
            if (jC < 64) { int2 t = s_sw[grp * 64 + jC]; sC = t.x; wC = __int_as_float(t.y); }
            else { sC = csr_src[beg + jC]; float v = as_in[sC] + adv;
                   v = (v > 0.f) ? v : NEG_SLOPE * v; wC = __expf(fminf(v, 60.f)); }
        }
        if (vD) {
            if (jD < 64) { int2 t = s_sw[grp * 64 + jD]; sD = t.x; wD = __int_as_float(t.y); }
            else { sD = csr_src[beg + jD]; float v = as_in[sD] + adv;
                   v = (v > 0.f) ? v : NEG_SLOPE * v; wD = __expf(fminf(v, 60.f)); }
        }
        uint4 pA={0u,0u,0u,0u}, pB={0u,0u,0u,0u}, pC={0u,0u,0u,0u}, pD={0u,0u,0u,0u};
        if (vA) pA = *(const uint4*)&hb_in[(long)sA * 64 + c8];
        if (vB) pB = *(const uint4*)&hb_in[(long)sB * 64 + c8];
        if (vC) pC = *(const uint4*)&hb_in[(long)sC * 64 + c8];
        if (vD) pD = *(const uint4*)&hb_in[(long)sD * 64 + c8];
        EDGE4_FMA(wA, pA) EDGE4_FMA(wB, pB) EDGE4_FMA(wC, pC) EDGE4_FMA(wD, pD)
        dsum += (wA + wB) + (wC + wD);
    }

    float a0 = A0.x, a1 = A0.y, a2 = A1.x, a3 = A1.y;
    float a4 = A2.x, a5 = A2.y, a6 = A3.x, a7 = A3.y;
    a0 += __shfl_xor(a0, 8, 64); a1 += __shfl_xor(a1, 8, 64);
    a2 += __shfl_xor(a2, 8, 64); a3 += __shfl_xor(a3, 8, 64);
    a4 += __shfl_xor(a4, 8, 64); a5 += __shfl_xor(a5, 8, 64);
    a6 += __shfl_xor(a6, 8, 64); a7 += __shfl_xor(a7, 8, 64);
    dsum += __shfl_xor(dsum, 8, 64);

    if (sub == 0) {   // lanes l16 0..7 hold channels c8..c8+7
        float inv = 1.f / dsum;
        float r[8] = {a0, a1, a2, a3, a4, a5, a6, a7};
#pragma unroll
        for (int k = 0; k < 8; ++k) {
            r[k] = r[k] * inv + bias[c8 + k];
            if (DO_ELU) r[k] = (r[k] > 0.f) ? r[k] : expm1f(r[k]);
        }
        long o = (long)node * 64 + c8;
        bool bfst = (OMODE == 0) || (*flag != 0u);
        if (bfst) {
            uint4 u;
            u.x = ((unsigned)__bfloat16_as_ushort(__float2bfloat16(r[0]))) |
                  (((unsigned)__bfloat16_as_ushort(__float2bfloat16(r[1]))) << 16);
            u.y = ((unsigned)__bfloat16_as_ushort(__float2bfloat16(r[2]))) |
                  (((unsigned)__bfloat16_as_ushort(__float2bfloat16(r[3]))) << 16);
            u.z = ((unsigned)__bfloat16_as_ushort(__float2bfloat16(r[4]))) |
                  (((unsigned)__bfloat16_as_ushort(__float2bfloat16(r[5]))) << 16);
            u.w = ((unsigned)__bfloat16_as_ushort(__float2bfloat16(r[6]))) |
                  (((unsigned)__bfloat16_as_ushort(__float2bfloat16(r[7]))) << 16);
            *(uint4*)&((unsigned short*)out)[o] = u;
        } else {
            float4 f0 = {r[0], r[1], r[2], r[3]};
            float4 f1 = {r[4], r[5], r[6], r[7]};
            *(float4*)&((float*)out)[o]     = f0;
            *(float4*)&((float*)out)[o + 4] = f1;
        }
    }
}

extern "C" void kernel_launch(void* const* d_in, const int* in_sizes, int n_in,
                              void* d_out, int out_size, void* d_ws, size_t ws_size,
                              hipStream_t stream)
{
    const void* x  = d_in[0];
    const int*  ei = (const int*)d_in[1];
    const void* pW1 = d_in[2],  *pas1 = d_in[3],  *pad1 = d_in[4],  *pb1 = d_in[5];
    const void* pW2 = d_in[6],  *pas2 = d_in[7],  *pad2 = d_in[8],  *pb2 = d_in[9];
    const void* pW3 = d_in[10], *pas3 = d_in[11], *pad3 = d_in[12], *pb3 = d_in[13];

    float* ws = (float*)d_ws;
    bf16*     hbA    = (bf16*)ws;                              // 6.4 MB
    bf16*     hbB    = (bf16*)(ws + (long)N_NODES * 32);       // 6.4 MB
    float*    asA    = ws + (long)N_NODES * 64;
    float*    adA    = asA + N_NODES;
    float*    asB    = adA + N_NODES;                          // ping-pong (R12)
    float*    adB    = asB + N_NODES;
    int*      cur256 = (int*)(adB + N_NODES);                  // NBUCK
    int*      rowptr = cur256 + NBUCK;                         // N+1
    int*      csr_src= rowptr + N_NODES + 1;                   // 3.4 MB
    unsigned* scratch= (unsigned*)(csr_src + ET_EDGES);        // NBUCK*CAP 6.4 MB
    float*    prm    = (float*)(scratch + (long)NBUCK * CAP);
    unsigned* flag   = (unsigned*)(prm + 20000);
    short*    wb2    = (short*)(prm + 20008);                  // 8192 shorts (hi+lo)
    short*    wb3    = wb2 + 8192;                             // 8192 shorts
    short*    wb1    = wb3 + 8192;                             // 16384 shorts (hi)

    float* W1 = prm;     float* as1 = W1 + 8192; float* ad1 = as1 + 64; float* b1 = ad1 + 64;
    float* W2 = b1 + 64; float* as2 = W2 + 4096; float* ad2 = as2 + 64; float* b2 = ad2 + 64;
    float* W3 = b2 + 64; float* as3 = W3 + 4096; float* ad3 = as3 + 64; float* b3 = ad3 + 64;

    PrepArgs pa;
    const void* srcs[12] = {pW1, pas1, pad1, pb1, pW2, pas2, pad2, pb2, pW3, pas3, pad3, pb3};
    float*      dsts[12] = {W1, as1, ad1, b1, W2, as2, ad2, b2, W3, as3, ad3, b3};
    int         ns[12]   = {8192, 64, 64, 64, 4096, 64, 64, 64, 4096, 64, 64, 64};
    for (int i = 0; i < 12; ++i) { pa.src[i] = srcs[i]; pa.dst[i] = dsts[i]; pa.n[i] = ns[i]; }
    prep<<<dim3(8, 16), 256, 0, stream>>>(
        pa, (const unsigned short*)pW1, pW2, pW3, wb1, wb2, wb3, flag, cur256);

    // ---------- Layer 1 GEMM (MFMA when bf16) fused with CSR binpass --------
    gemm1_bin<<<BIN_GRID + GEMM_GRID, 256, 0, stream>>>(
        x, W1, wb1, as1, ad1, flag, hbA, asA, adA, ei, cur256, scratch);
    fine_scatter<<<NBUCK, 256, 0, stream>>>(cur256, scratch, csr_src, rowptr);

    // ---------- gat1 + gemm2 fused: hbA/asA -> hbB/asB ----------
    gat_gemm<<<GAT_GRID, 256, 0, stream>>>(
        rowptr, csr_src, asA, adA, (const unsigned short*)hbA, b1,
        wb2, as2, ad2, flag, hbB, asB, adB);

    // ---------- gat2 + gemm3 fused: hbB/asB -> hbA/asA ----------
    gat_gemm<<<GAT_GRID, 256, 0, stream>>>(
        rowptr, csr_src, asB, adB, (const unsigned short*)hbB, b2,
        wb3, as3, ad3, flag, hbA, asA, adA);

    // ---------- gat3 (final output) ----------
    gat_gather<false, 1><<<GAT_GRID, 256, 0, stream>>>(
        rowptr, csr_src, asA, adA, (const unsigned short*)hbA, b3, d_out, flag);
}